// Round 21
// baseline (44.389 us; speedup 1.0000x reference)
//
#include <hip/hip_runtime.h>
#include <hip/hip_bf16.h>

// Hopf oscillator scan: B=32, T=1000, D=512.
// THREE-wave specialization (R19 base, 43.3us best, sc1-nt drainer stores).
// R20 change: CONSUMER READ HOIST — at round n the consumer prefetches body
// n+1's inputs into ping-pong register buffers (xrA/xrB, static indexing via
// 2-unrolled loop) and computes body n from registers filled last round.
// The 40-step chain has zero lgkm dependency in-round: read latency and the
// post-barrier LDS burst contention (loader DMA + drainer reads) leave the
// critical path. Support: loader issues 3 bodies ahead (RING=4) so body n+2
// is guaranteed at barrier n -> body n+1 always readable during round n.
//   wave 0 (consumer): prefetch n+1 -> regs, chain n from regs, OUT write
//     burst, lgkm seal.
//   wave 1 (loader): global_load_lds dwordx4, 4-deep ring, 3 bodies ahead,
//     steady wait vmcnt(20) (loads-only queue).
//   wave 2 (drainer): OUT[n-1] -> buffer-store sc1-nt, off critical path.

#define B 32
#define T 1000
#define D 512
#define DTc 0.001f
#define K_IN 0.005f               // INPUT_SCALER * DT
#define KREV 7.95774715e-4f       // INPUT_SCALER * DT / (2*pi)
#define U 40                      // steps per body
#define NB (T / U)                // 25 bodies
#define NOPS (U / 4)              // 10 glds/drain ops per array per body
#define RING 4                    // IN ring depth

typedef float v4f __attribute__((ext_vector_type(4)));
typedef unsigned int v4u __attribute__((ext_vector_type(4)));
typedef const __attribute__((address_space(1))) float gfloat;
typedef __attribute__((address_space(3))) float lfloat;

#define SCHEDB() __builtin_amdgcn_sched_barrier(0)
#define BAR()    __builtin_amdgcn_s_barrier()
// s_waitcnt simm16 (gfx9): [3:0]=vmcnt lo, [15:14]=vmcnt hi, [6:4]=expcnt, [11:8]=lgkmcnt
#define W_LGKM0  0xC07F   // lgkmcnt(0) only
#define W_VM0    0x0F70   // vmcnt(0)  only
#define W_VM20   0x4F74   // vmcnt(20) only

// gfx94x/95x CPol for buffer ops: bit0=SC0, bit1=NT, bit4=SC1
#define AUX_NT_SC1 18

__global__ __launch_bounds__(192, 1) void hopf_scan(
    const float* __restrict__ Xr, const float* __restrict__ Xi,
    const float* __restrict__ om,
    float* __restrict__ zr, float* __restrict__ zi) {
    const int tid = threadIdx.x;
    const int bb = blockIdx.x;            // 0..255
    const int b = bb >> 3;
    const int dblk = (bb & 7) << 6;       // 64-d block
    const size_t blkoff = (size_t)b * (T * D) + dblk;

    __shared__ __align__(16) float INr[RING][U][64];   // 4-deep input ring
    __shared__ __align__(16) float INi[RING][U][64];
    __shared__ __align__(16) float OUTr[2][U][64];     // double-buffered out
    __shared__ __align__(16) float OUTi[2][U][64];

    if (tid < 64) {
        // ---------------- wave 0: consumer (LDS + VALU only) ----------------
        const int i = tid;
        // rev/step: f_Hz * dt = (om*10 + 0.1) * dt
        const float od = __builtin_fmaf(om[dblk + i], 10.0f, 0.1f) * DTc;
        float r = 1.0f, phi = 0.0f, c = 1.0f, s = 0.0f;  // phi in revolutions

        float xrA[U], xiA[U], xrB[U], xiB[U];

        auto prefetch = [&](int slot, float (&xr)[U], float (&xi)[U]) {
#pragma unroll
            for (int t = 0; t < U; ++t) {
                xr[t] = INr[slot][t][i];
                xi[t] = INi[slot][t][i];
            }
        };
        auto body = [&](const float (&xr)[U], const float (&xi)[U], int ob) {
            float our[U], oui[U];
#pragma unroll
            for (int t = 0; t < U; ++t) {
                const float omr2 = __builtin_fmaf(-r, r, 1.0f);   // 1 - r^2
                r = __builtin_fmaf(omr2 * r, DTc, r);             // + cubic*dt
                r = __builtin_fmaf(K_IN * xr[t], c, r);           // + K*xr*cos
                phi = __builtin_fmaf(-(KREV * xi[t]), s, phi + od);
                s = __builtin_amdgcn_sinf(phi);   // v_sin: input in revs
                c = __builtin_amdgcn_cosf(phi);
                our[t] = r * c;
                oui[t] = r * s;
            }
            SCHEDB();
#pragma unroll
            for (int t = 0; t < U; ++t) {
                OUTr[ob][t][i] = our[t];
                OUTi[ob][t][i] = oui[t];
            }
            __builtin_amdgcn_s_waitcnt(W_LGKM0);  // OUT (+prefetch) complete
            SCHEDB();
            BAR();
        };

        BAR();                            // bodies 0,1 staged by loader
        prefetch(0, xrA, xiA);            // one-time serialized read of body 0
        SCHEDB();
        for (int n = 0; n < NB - 1; n += 2) {
            // round n: issue body n+1 reads (no in-round consumers), chain n
            prefetch((n + 1) & 3, xrB, xiB);
            SCHEDB();                     // pin early issue (no sinking)
            body(xrA, xiA, n & 1);
            // round n+1
            prefetch((n + 2) & 3, xrA, xiA);
            SCHEDB();
            body(xrB, xiB, (n + 1) & 1);
        }
        body(xrA, xiA, (NB - 1) & 1);     // round 24 (body 24 read @ round 23)
    } else if (tid < 128) {
        // ---------------- wave 1: loader (global->LDS only) -----------------
        const int i = tid - 64;
        const int ts = i >> 4;            // sub-step 0..3 of a glds op
        const int dq = (i & 15) << 2;     // d quad
        const float* __restrict__ xr_blk = Xr + blkoff;
        const float* __restrict__ xi_blk = Xi + blkoff;

        auto issueglds = [&](int body, int buf) {
#pragma unroll
            for (int k = 0; k < NOPS; ++k) {
                const size_t off = (size_t)(body * U + 4 * k + ts) * D + dq;
                __builtin_amdgcn_global_load_lds((gfloat*)(xr_blk + off),
                                                 (lfloat*)&INr[buf][4 * k][0], 16, 0, 0);
                __builtin_amdgcn_global_load_lds((gfloat*)(xi_blk + off),
                                                 (lfloat*)&INi[buf][4 * k][0], 16, 0, 0);
            }
        };

        // prologue: bodies 0,1,2 in flight; need 0 AND 1 landed at barrier
        // (consumer prefetches body 1 during round 0): newer = body 2's 20.
        issueglds(0, 0);
        issueglds(1, 1);
        issueglds(2, 2);
        __builtin_amdgcn_s_waitcnt(W_VM20);
        SCHEDB();
        BAR();

        for (int n = 0; n < NB; ++n) {
            if (n + 3 < NB) issueglds(n + 3, (n + 3) & 3);
            SCHEDB();
            if (n + 2 < NB) {
                // guarantee body n+2 by barrier n: newer = body n+3's 20.
                if (n + 3 < NB) __builtin_amdgcn_s_waitcnt(W_VM20);
                else            __builtin_amdgcn_s_waitcnt(W_VM0);
            }
            SCHEDB();
            BAR();
        }
    } else {
        // ---------------- wave 2: drainer (LDS->global only) ----------------
        const int i = tid - 128;
        const int ts = i >> 4;
        const int dq = (i & 15) << 2;
        // opaque buffer resources: stride=0, num_records=disabled, raw flags
        const __amdgpu_buffer_rsrc_t srd_r =
            __builtin_amdgcn_make_buffer_rsrc((void*)zr, (short)0,
                                              (int)0xffffffff, 0x00020000);
        const __amdgpu_buffer_rsrc_t srd_i =
            __builtin_amdgcn_make_buffer_rsrc((void*)zi, (short)0,
                                              (int)0xffffffff, 0x00020000);
        const unsigned boff = (unsigned)blkoff;   // block base, elements

        auto drainbody = [&](int body) {
            const int ob = body & 1;
#pragma unroll
            for (int k = 0; k < NOPS; ++k) {
                const unsigned off = (boff + (unsigned)((body * U + 4 * k + ts) * D + dq)) * 4u;
                const v4u vr = *reinterpret_cast<const v4u*>(&OUTr[ob][4 * k + ts][dq]);
                const v4u vi = *reinterpret_cast<const v4u*>(&OUTi[ob][4 * k + ts][dq]);
                // sc1|nt: keep the output stream out of the input-resident L3
                __builtin_amdgcn_raw_buffer_store_b128(vr, srd_r, off, 0, AUX_NT_SC1);
                __builtin_amdgcn_raw_buffer_store_b128(vi, srd_i, off, 0, AUX_NT_SC1);
            }
        };

        BAR();                            // match loader/consumer prologue
        for (int n = 0; n < NB; ++n) {
            // OUT[n-1] was sealed at barrier n-1; drain it during round n.
            if (n >= 1) drainbody(n - 1);
            SCHEDB();
            BAR();
        }
        drainbody(NB - 1);                // sealed at final barrier
    }
}

extern "C" void kernel_launch(void* const* d_in, const int* in_sizes, int n_in,
                              void* d_out, int out_size, void* d_ws, size_t ws_size,
                              hipStream_t stream) {
    const float* Xr = (const float*)d_in[0];
    const float* Xi = (const float*)d_in[1];
    const float* om = (const float*)d_in[2];
    float* zr = (float*)d_out;
    float* zi = zr + (size_t)B * T * D;   // tuple output 2, flat-concatenated

    hopf_scan<<<dim3(B * D / 64), dim3(192), 0, stream>>>(Xr, Xi, om, zr, zi);
}